// Round 1
// baseline (605.392 us; speedup 1.0000x reference)
//
#include <hip/hip_runtime.h>

typedef unsigned short bhalf;          // bf16 bits
typedef __attribute__((ext_vector_type(4))) float    f32x4;
typedef __attribute__((ext_vector_type(8))) short    s16x8;
typedef __attribute__((ext_vector_type(4))) float    floatx4;
typedef __attribute__((ext_vector_type(4))) unsigned int u32x4;
typedef __attribute__((ext_vector_type(4))) unsigned short u16x4;

#define B_  2
#define S_  2048
#define HID_ 2048
#define NH_ 16
#define HD_ 128
#define M_  (B_*S_)          // 4096

__device__ __forceinline__ bhalf f32_to_bf16(float f) {
    union { float f; unsigned int u; } v; v.f = f;
    unsigned int r = v.u + 0x7FFFu + ((v.u >> 16) & 1u);   // RNE
    return (bhalf)(r >> 16);
}
__device__ __forceinline__ float bf16_to_f32(bhalf h) {
    union { unsigned int u; float f; } v; v.u = ((unsigned int)h) << 16;
    return v.f;
}

// ---------------- cast fp32 -> bf16, vectorized ----------------
__global__ __launch_bounds__(256) void cast_f32_bf16(const float* __restrict__ src,
                                                     bhalf* __restrict__ dst, int n4) {
    int idx = blockIdx.x * 256 + threadIdx.x;
    if (idx < n4) {
        floatx4 f = *(const floatx4*)(src + (size_t)idx * 4);
        u16x4 o;
        o.x = f32_to_bf16(f.x); o.y = f32_to_bf16(f.y);
        o.z = f32_to_bf16(f.z); o.w = f32_to_bf16(f.w);
        *(u16x4*)(dst + (size_t)idx * 4) = o;
    }
}

// ---------------- fused QKV GEMM: out = hs @ W^T + b (bf16 in, bf16 out) ----
// A: (4096 x 2048) bf16, W: (2048 x 2048) bf16 row-major (i.e. B^T layout).
// 128x128 tile, BK=32, 4 waves (2x2), each wave 64x64 via 4x4 MFMA 16x16x32.
__global__ __launch_bounds__(256) void qkv_gemm(const bhalf* __restrict__ A,
                                                const bhalf* __restrict__ Wb,
                                                const float* __restrict__ bq,
                                                const float* __restrict__ bk,
                                                const float* __restrict__ bv,
                                                bhalf* __restrict__ Out) {
    __shared__ __align__(16) bhalf As[128 * 32];
    __shared__ __align__(16) bhalf Bs[128 * 32];
    const int tid  = threadIdx.x;
    const int lane = tid & 63, w = tid >> 6;
    const int wy = w >> 1, wx = w & 1;
    const int quad = lane >> 4, l = lane & 15;
    const int m0 = blockIdx.x * 128, n0 = blockIdx.y * 128;
    const int z  = blockIdx.z;
    const bhalf* W    = Wb + (size_t)z * HID_ * HID_;
    const float* bias = (z == 0) ? bq : (z == 1) ? bk : bv;
    bhalf* out        = Out + (size_t)z * M_ * HID_;

    f32x4 acc[4][4] = {};

    for (int kt = 0; kt < HID_; kt += 32) {
#pragma unroll
        for (int ss = 0; ss < 2; ++ss) {
            int flat8 = tid + ss * 256;            // 0..511 slots of 8 elems
            int row = flat8 >> 2, cg = flat8 & 3;  // 128 rows x 4 groups
            u32x4 va = *(const u32x4*)(A + (size_t)(m0 + row) * HID_ + kt + cg * 8);
            u32x4 vb = *(const u32x4*)(W + (size_t)(n0 + row) * HID_ + kt + cg * 8);
            *(u32x4*)(As + flat8 * 8) = va;
            *(u32x4*)(Bs + flat8 * 8) = vb;
        }
        __syncthreads();
        s16x8 af[4], bfr[4];
#pragma unroll
        for (int mt = 0; mt < 4; ++mt)
            af[mt] = *(const s16x8*)(As + (wy * 64 + mt * 16 + l) * 32 + quad * 8);
#pragma unroll
        for (int nt = 0; nt < 4; ++nt)
            bfr[nt] = *(const s16x8*)(Bs + (wx * 64 + nt * 16 + l) * 32 + quad * 8);
#pragma unroll
        for (int mt = 0; mt < 4; ++mt)
#pragma unroll
            for (int nt = 0; nt < 4; ++nt)
                acc[mt][nt] = __builtin_amdgcn_mfma_f32_16x16x32_bf16(
                    af[mt], bfr[nt], acc[mt][nt], 0, 0, 0);
        __syncthreads();
    }
#pragma unroll
    for (int mt = 0; mt < 4; ++mt) {
#pragma unroll
        for (int nt = 0; nt < 4; ++nt) {
            int col = n0 + wx * 64 + nt * 16 + l;
            float bv_ = bias[col];
#pragma unroll
            for (int r = 0; r < 4; ++r) {
                int row = m0 + wy * 64 + mt * 16 + quad * 4 + r;
                out[(size_t)row * HID_ + col] = f32_to_bf16(acc[mt][nt][r] + bv_);
            }
        }
    }
}

// ---------------- RoPE in place on Q and K (first 64 dims per head) --------
__global__ __launch_bounds__(256) void rope_kernel(bhalf* __restrict__ Qb,
                                                   bhalf* __restrict__ Kb) {
    int flat = blockIdx.x * 256 + threadIdx.x;   // B*S*NH*32 = 2,097,152 threads
    int i = flat & 31;
    int h = (flat >> 5) & 15;
    int s = (flat >> 9) & 2047;
    int b = flat >> 20;
    size_t base = ((size_t)(b * S_ + s)) * HID_ + h * HD_ + 2 * i;
    // inv_freq = 10000^(-i/32) ; ang = s * inv_freq (all fp32, like reference)
    float inv = expf(-(float)i * 0.2878231366242557f);   // ln(10000)/32
    float ang = (float)s * inv;
    float c = cosf(ang), sn = sinf(ang);
    {
        unsigned int q = *(const unsigned int*)(Qb + base);
        float x0 = bf16_to_f32((bhalf)(q & 0xffff));
        float x1 = bf16_to_f32((bhalf)(q >> 16));
        float y0 = x0 * c - x1 * sn;
        float y1 = x1 * c + x0 * sn;
        unsigned int o = (unsigned int)f32_to_bf16(y0) | ((unsigned int)f32_to_bf16(y1) << 16);
        *(unsigned int*)(Qb + base) = o;
    }
    {
        unsigned int k = *(const unsigned int*)(Kb + base);
        float x0 = bf16_to_f32((bhalf)(k & 0xffff));
        float x1 = bf16_to_f32((bhalf)(k >> 16));
        float y0 = x0 * c - x1 * sn;
        float y1 = x1 * c + x0 * sn;
        unsigned int o = (unsigned int)f32_to_bf16(y0) | ((unsigned int)f32_to_bf16(y1) << 16);
        *(unsigned int*)(Kb + base) = o;
    }
}

// ---------------- V transpose per (b,h): (S x HD) -> (HD x S) --------------
__global__ __launch_bounds__(256) void v_transpose(const bhalf* __restrict__ Vb,
                                                   bhalf* __restrict__ VT) {
    __shared__ bhalf tile[32 * 33];
    int t = threadIdx.x;
    int s0 = blockIdx.x * 32, d0 = blockIdx.y * 32, bh = blockIdx.z;
    int b = bh >> 4, h = bh & 15;
    {
        int sl = t >> 3, dg = t & 7;
        u16x4 v = *(const u16x4*)(Vb + (size_t)(b * S_ + s0 + sl) * HID_ + h * HD_ + d0 + dg * 4);
        tile[sl * 33 + dg * 4 + 0] = v.x;
        tile[sl * 33 + dg * 4 + 1] = v.y;
        tile[sl * 33 + dg * 4 + 2] = v.z;
        tile[sl * 33 + dg * 4 + 3] = v.w;
    }
    __syncthreads();
    {
        int dl = t >> 3, sg = t & 7;
        u16x4 v;
        v.x = tile[(sg * 4 + 0) * 33 + dl];
        v.y = tile[(sg * 4 + 1) * 33 + dl];
        v.z = tile[(sg * 4 + 2) * 33 + dl];
        v.w = tile[(sg * 4 + 3) * 33 + dl];
        *(u16x4*)(VT + ((size_t)(b * NH_ + h) * HD_ + d0 + dl) * S_ + s0 + sg * 4) = v;
    }
}

// ---------------- flash attention ------------------------------------------
// grid (S/64 qtiles, B*NH). block = 256 = 4 waves; wave w owns q rows
// [q0+16w, q0+16w+16). K/V chunks of 32 keys staged in LDS.
__global__ __launch_bounds__(256) void flash_attn(const bhalf* __restrict__ Qb,
                                                  const bhalf* __restrict__ Kb,
                                                  const bhalf* __restrict__ VT,
                                                  const float* __restrict__ amask,
                                                  float* __restrict__ out) {
    __shared__ __align__(16) bhalf Ks[32 * 128];    // [key][d]
    __shared__ __align__(16) bhalf VTs[128 * 32];   // [d][key]
    __shared__ __align__(16) bhalf Ps[4 * 16 * 32]; // per-wave P tile [q][key]
    const int tid = threadIdx.x, lane = tid & 63, w = tid >> 6;
    const int quad = lane >> 4, l = lane & 15;
    const int qt = blockIdx.x, bh = blockIdx.y;
    const int b = bh >> 4, h = bh & 15;
    const int q0 = qt * 64;
    const int qrow_base = q0 + w * 16;

    // preload Q A-fragments: A[m=l][k = ks*32 + quad*8 + j]
    s16x8 qf[4];
    const bhalf* Qrow = Qb + (size_t)(b * S_ + qrow_base + l) * HID_ + h * HD_;
#pragma unroll
    for (int ks = 0; ks < 4; ++ks)
        qf[ks] = *(const s16x8*)(Qrow + ks * 32 + quad * 8);

    float m_run[4] = {-1e30f, -1e30f, -1e30f, -1e30f};
    float l_run[4] = {0.f, 0.f, 0.f, 0.f};
    f32x4 accO[8] = {};

    const int nch = (q0 + 64) >> 5;
    for (int kc = 0; kc < nch; ++kc) {
        __syncthreads();
#pragma unroll
        for (int ss = 0; ss < 2; ++ss) {
            int flat8 = tid + ss * 256;
            {   // K chunk: 32 keys x 128 d
                int row = flat8 >> 4, cg = flat8 & 15;
                *(u32x4*)(Ks + flat8 * 8) = *(const u32x4*)(
                    Kb + (size_t)(b * S_ + kc * 32 + row) * HID_ + h * HD_ + cg * 8);
            }
            {   // VT chunk: 128 d x 32 keys
                int d = flat8 >> 2, cg = flat8 & 3;
                *(u32x4*)(VTs + flat8 * 8) = *(const u32x4*)(
                    VT + ((size_t)(b * NH_ + h) * HD_ + d) * S_ + kc * 32 + cg * 8);
            }
        }
        __syncthreads();

        if (kc * 32 <= qrow_base + 15) {   // not fully masked for this wave
            f32x4 sc[2] = {};
#pragma unroll
            for (int nt = 0; nt < 2; ++nt)
#pragma unroll
                for (int ks = 0; ks < 4; ++ks) {
                    s16x8 kf = *(const s16x8*)(Ks + (nt * 16 + l) * 128 + ks * 32 + quad * 8);
                    sc[nt] = __builtin_amdgcn_mfma_f32_16x16x32_bf16(qf[ks], kf, sc[nt], 0, 0, 0);
                }
            const float scale = 0.08838834764831845f;   // 1/sqrt(128)
            float am[2];
#pragma unroll
            for (int nt = 0; nt < 2; ++nt)
                am[nt] = amask[b * S_ + kc * 32 + nt * 16 + l];
            float p[2][4], rm[4];
#pragma unroll
            for (int r = 0; r < 4; ++r) {
                int qrow = qrow_base + quad * 4 + r;
#pragma unroll
                for (int nt = 0; nt < 2; ++nt) {
                    int key = kc * 32 + nt * 16 + l;
                    float v = sc[nt][r] * scale;
                    v = (key > qrow) ? -10000.0f : v;
                    p[nt][r] = v + am[nt];
                }
                float mx = fmaxf(p[0][r], p[1][r]);
#pragma unroll
                for (int msk = 1; msk < 16; msk <<= 1)
                    mx = fmaxf(mx, __shfl_xor(mx, msk, 64));
                rm[r] = mx;
            }
#pragma unroll
            for (int r = 0; r < 4; ++r) {
                float m_new = fmaxf(m_run[r], rm[r]);
                float alpha = __expf(m_run[r] - m_new);
                float s0e = __expf(p[0][r] - m_new);
                float s1e = __expf(p[1][r] - m_new);
                p[0][r] = s0e; p[1][r] = s1e;
                float rs = s0e + s1e;
#pragma unroll
                for (int msk = 1; msk < 16; msk <<= 1)
                    rs += __shfl_xor(rs, msk, 64);
                l_run[r] = l_run[r] * alpha + rs;
                m_run[r] = m_new;
#pragma unroll
                for (int nt = 0; nt < 8; ++nt) accO[nt][r] *= alpha;
            }
            // P: C-layout (row=quad*4+r, col=nt*16+l) -> LDS row-major 16x32
#pragma unroll
            for (int r = 0; r < 4; ++r)
#pragma unroll
                for (int nt = 0; nt < 2; ++nt)
                    Ps[w * 512 + (quad * 4 + r) * 32 + nt * 16 + l] = f32_to_bf16(p[nt][r]);
            // P A-fragment: A[m=l][k=quad*8+j]
            s16x8 pf = *(const s16x8*)(Ps + w * 512 + l * 32 + quad * 8);
#pragma unroll
            for (int nt = 0; nt < 8; ++nt) {
                s16x8 vf = *(const s16x8*)(VTs + (nt * 16 + l) * 32 + quad * 8);
                accO[nt] = __builtin_amdgcn_mfma_f32_16x16x32_bf16(pf, vf, accO[nt], 0, 0, 0);
            }
        }
    }
    // epilogue: O /= l, fp32 out (B,S,HID)
#pragma unroll
    for (int nt = 0; nt < 8; ++nt) {
        int col = h * HD_ + nt * 16 + l;
#pragma unroll
        for (int r = 0; r < 4; ++r) {
            int row = b * S_ + q0 + w * 16 + quad * 4 + r;
            out[(size_t)row * HID_ + col] = accO[nt][r] / l_run[r];
        }
    }
}

extern "C" void kernel_launch(void* const* d_in, const int* in_sizes, int n_in,
                              void* d_out, int out_size, void* d_ws, size_t ws_size,
                              hipStream_t stream) {
    const float* hs    = (const float*)d_in[0];
    const float* amask = (const float*)d_in[1];
    const float* Wq    = (const float*)d_in[2];
    const float* bq    = (const float*)d_in[3];
    const float* Wk    = (const float*)d_in[4];
    const float* bk    = (const float*)d_in[5];
    const float* Wv    = (const float*)d_in[6];
    const float* bv    = (const float*)d_in[7];
    float* out = (float*)d_out;

    bhalf* hsb = (bhalf*)d_ws;              // 8,388,608 elems
    bhalf* wqb = hsb + 8388608;             // 3 x 4,194,304 (contiguous)
    bhalf* wkb = wqb + 4194304;
    bhalf* wvb = wkb + 4194304;
    bhalf* Qb  = wvb + 4194304;             // 3 x 8,388,608 (contiguous)
    bhalf* Kb  = Qb + 8388608;
    bhalf* Vb  = Kb + 8388608;
    bhalf* VTb = Vb + 8388608;              // total ~109 MB

    cast_f32_bf16<<<8192, 256, 0, stream>>>(hs, hsb, 2097152);
    cast_f32_bf16<<<4096, 256, 0, stream>>>(Wq, wqb, 1048576);
    cast_f32_bf16<<<4096, 256, 0, stream>>>(Wk, wkb, 1048576);
    cast_f32_bf16<<<4096, 256, 0, stream>>>(Wv, wvb, 1048576);
    qkv_gemm<<<dim3(32, 16, 3), 256, 0, stream>>>(hsb, wqb, bq, bk, bv, Qb);
    rope_kernel<<<8192, 256, 0, stream>>>(Qb, Kb);
    v_transpose<<<dim3(64, 4, 32), 256, 0, stream>>>(Vb, VTb);
    flash_attn<<<dim3(32, 32), 256, 0, stream>>>(Qb, Kb, VTb, amask, out);
}

// Round 2
// 428.695 us; speedup vs baseline: 1.4122x; 1.4122x over previous
//
#include <hip/hip_runtime.h>

typedef unsigned short bhalf;          // bf16 bits
typedef __attribute__((ext_vector_type(4))) float    f32x4;
typedef __attribute__((ext_vector_type(8))) short    s16x8;
typedef __attribute__((ext_vector_type(4))) float    floatx4;
typedef __attribute__((ext_vector_type(4))) unsigned int u32x4;
typedef __attribute__((ext_vector_type(4))) unsigned short u16x4;

#define B_  2
#define S_  2048
#define HID_ 2048
#define NH_ 16
#define HD_ 128
#define M_  (B_*S_)          // 4096

__device__ __forceinline__ bhalf f32_to_bf16(float f) {
    union { float f; unsigned int u; } v; v.f = f;
    unsigned int r = v.u + 0x7FFFu + ((v.u >> 16) & 1u);   // RNE
    return (bhalf)(r >> 16);
}
__device__ __forceinline__ float bf16_to_f32(bhalf h) {
    union { unsigned int u; float f; } v; v.u = ((unsigned int)h) << 16;
    return v.f;
}

// async global->LDS, 16B per lane; LDS dest = wave-uniform base + lane*16
__device__ __forceinline__ void gl_lds16(const void* g, void* l) {
    __builtin_amdgcn_global_load_lds(
        (const __attribute__((address_space(1))) void*)g,
        (__attribute__((address_space(3))) void*)l, 16, 0, 0);
}

// ---------------- cast fp32 -> bf16, vectorized ----------------
__global__ __launch_bounds__(256) void cast_f32_bf16(const float* __restrict__ src,
                                                     bhalf* __restrict__ dst, int n4) {
    int idx = blockIdx.x * 256 + threadIdx.x;
    if (idx < n4) {
        floatx4 f = *(const floatx4*)(src + (size_t)idx * 4);
        u16x4 o;
        o.x = f32_to_bf16(f.x); o.y = f32_to_bf16(f.y);
        o.z = f32_to_bf16(f.z); o.w = f32_to_bf16(f.w);
        *(u16x4*)(dst + (size_t)idx * 4) = o;
    }
}

// ---------------- fused QKV GEMM (m97 rung): out = hs @ W^T + b ------------
// 128x128 tile, BK=32, global_load_lds staging, XOR-swizzled LDS (cg ^= (row>>1)&3)
__global__ __launch_bounds__(256) void qkv_gemm(const bhalf* __restrict__ A,
                                                const bhalf* __restrict__ Wb,
                                                const float* __restrict__ bq,
                                                const float* __restrict__ bk,
                                                const float* __restrict__ bv,
                                                bhalf* __restrict__ Out) {
    __shared__ __align__(16) bhalf As[128 * 32];
    __shared__ __align__(16) bhalf Bs[128 * 32];
    const int tid  = threadIdx.x;
    const int lane = tid & 63, w = tid >> 6;
    const int wy = w >> 1, wx = w & 1;
    const int quad = lane >> 4, l = lane & 15;
    const int m0 = blockIdx.x * 128, n0 = blockIdx.y * 128;
    const int z  = blockIdx.z;
    const bhalf* W    = Wb + (size_t)z * HID_ * HID_;
    const float* bias = (z == 0) ? bq : (z == 1) ? bk : bv;
    bhalf* out        = Out + (size_t)z * M_ * HID_;

    f32x4 acc[4][4] = {};

    for (int kt = 0; kt < HID_; kt += 32) {
#pragma unroll
        for (int j = 0; j < 2; ++j) {
            int slot0 = j * 256 + w * 64;          // wave-uniform
            int slot  = slot0 + lane;
            int row = slot >> 2;
            int cg  = (slot & 3) ^ ((row >> 1) & 3);   // swizzle
            gl_lds16(A + (size_t)(m0 + row) * HID_ + kt + cg * 8, As + slot0 * 8);
            gl_lds16(W + (size_t)(n0 + row) * HID_ + kt + cg * 8, Bs + slot0 * 8);
        }
        __syncthreads();
        s16x8 af[4], bfr[4];
#pragma unroll
        for (int mt = 0; mt < 4; ++mt) {
            int row = wy * 64 + mt * 16 + l;
            int cgs = quad ^ ((row >> 1) & 3);
            af[mt] = *(const s16x8*)(As + (row * 4 + cgs) * 8);
        }
#pragma unroll
        for (int nt = 0; nt < 4; ++nt) {
            int row = wx * 64 + nt * 16 + l;
            int cgs = quad ^ ((row >> 1) & 3);
            bfr[nt] = *(const s16x8*)(Bs + (row * 4 + cgs) * 8);
        }
#pragma unroll
        for (int mt = 0; mt < 4; ++mt)
#pragma unroll
            for (int nt = 0; nt < 4; ++nt)
                acc[mt][nt] = __builtin_amdgcn_mfma_f32_16x16x32_bf16(
                    af[mt], bfr[nt], acc[mt][nt], 0, 0, 0);
        __syncthreads();
    }
#pragma unroll
    for (int mt = 0; mt < 4; ++mt) {
#pragma unroll
        for (int nt = 0; nt < 4; ++nt) {
            int col = n0 + wx * 64 + nt * 16 + l;
            float bv_ = bias[col];
#pragma unroll
            for (int r = 0; r < 4; ++r) {
                int row = m0 + wy * 64 + mt * 16 + quad * 4 + r;
                out[(size_t)row * HID_ + col] = f32_to_bf16(acc[mt][nt][r] + bv_);
            }
        }
    }
}

// ---------------- RoPE in place on Q and K (first 64 dims per head) --------
__global__ __launch_bounds__(256) void rope_kernel(bhalf* __restrict__ Qb,
                                                   bhalf* __restrict__ Kb) {
    int flat = blockIdx.x * 256 + threadIdx.x;
    int i = flat & 31;
    int h = (flat >> 5) & 15;
    int s = (flat >> 9) & 2047;
    int b = flat >> 20;
    size_t base = ((size_t)(b * S_ + s)) * HID_ + h * HD_ + 2 * i;
    float inv = expf(-(float)i * 0.2878231366242557f);   // ln(10000)/32
    float ang = (float)s * inv;
    float c = cosf(ang), sn = sinf(ang);
    {
        unsigned int q = *(const unsigned int*)(Qb + base);
        float x0 = bf16_to_f32((bhalf)(q & 0xffff));
        float x1 = bf16_to_f32((bhalf)(q >> 16));
        float y0 = x0 * c - x1 * sn;
        float y1 = x1 * c + x0 * sn;
        unsigned int o = (unsigned int)f32_to_bf16(y0) | ((unsigned int)f32_to_bf16(y1) << 16);
        *(unsigned int*)(Qb + base) = o;
    }
    {
        unsigned int k = *(const unsigned int*)(Kb + base);
        float x0 = bf16_to_f32((bhalf)(k & 0xffff));
        float x1 = bf16_to_f32((bhalf)(k >> 16));
        float y0 = x0 * c - x1 * sn;
        float y1 = x1 * c + x0 * sn;
        unsigned int o = (unsigned int)f32_to_bf16(y0) | ((unsigned int)f32_to_bf16(y1) << 16);
        *(unsigned int*)(Kb + base) = o;
    }
}

// ---------------- V transpose per (b,h): (S x HD) -> (HD x S) --------------
__global__ __launch_bounds__(256) void v_transpose(const bhalf* __restrict__ Vb,
                                                   bhalf* __restrict__ VT) {
    __shared__ bhalf tile[32 * 33];
    int t = threadIdx.x;
    int s0 = blockIdx.x * 32, d0 = blockIdx.y * 32, bh = blockIdx.z;
    int b = bh >> 4, h = bh & 15;
    {
        int sl = t >> 3, dg = t & 7;
        u16x4 v = *(const u16x4*)(Vb + (size_t)(b * S_ + s0 + sl) * HID_ + h * HD_ + d0 + dg * 4);
        tile[sl * 33 + dg * 4 + 0] = v.x;
        tile[sl * 33 + dg * 4 + 1] = v.y;
        tile[sl * 33 + dg * 4 + 2] = v.z;
        tile[sl * 33 + dg * 4 + 3] = v.w;
    }
    __syncthreads();
    {
        int dl = t >> 3, sg = t & 7;
        u16x4 v;
        v.x = tile[(sg * 4 + 0) * 33 + dl];
        v.y = tile[(sg * 4 + 1) * 33 + dl];
        v.z = tile[(sg * 4 + 2) * 33 + dl];
        v.w = tile[(sg * 4 + 3) * 33 + dl];
        *(u16x4*)(VT + ((size_t)(b * NH_ + h) * HD_ + d0 + dl) * S_ + s0 + sg * 4) = v;
    }
}

// ---------------- flash attention, paired q-tiles --------------------------
// Block handles q-tiles qt (lo) and 31-qt (hi), 64 rows each; wave w owns
// 16 rows of each. 64-key chunks staged once, shared by both tiles.
// Swizzled LDS: Ks [key][dg8] slot=key*16+(dg^key low3); VTs [d][kg8]
// slot=d*8+(kg^d low3); Ps per (wave,tile) [m][kg8] slot=m*8+(kg^fswz(m)).
#define MASKV (-10000.0f)

__device__ __forceinline__ void softmax_tile(f32x4* sc, float* m_run, float* l_run,
        f32x4* accO, bhalf* Pw, int row_base, bool diag, int key0,
        const float* am, int quad, int l) {
#pragma unroll
    for (int r = 0; r < 4; ++r) {
        const int qrow = row_base + quad * 4 + r;
        float p[4];
#pragma unroll
        for (int nt = 0; nt < 4; ++nt) {
            float v = sc[nt][r] * 0.08838834764831845f;   // 1/sqrt(128)
            if (diag) { int key = key0 + nt * 16 + l; v = (key > qrow) ? MASKV : v; }
            p[nt] = v + am[nt];
        }
        float mx = fmaxf(fmaxf(p[0], p[1]), fmaxf(p[2], p[3]));
#pragma unroll
        for (int msk = 1; msk < 16; msk <<= 1) mx = fmaxf(mx, __shfl_xor(mx, msk, 64));
        float m_new = fmaxf(m_run[r], mx);
        float rs = 0.f;
        const int m  = quad * 4 + r;
        const int fm = (m + (m >> 3)) & 7;
#pragma unroll
        for (int nt = 0; nt < 4; ++nt) {
            float e = __expf(p[nt] - m_new);
            rs += e;
            int key = nt * 16 + l;
            Pw[(m * 8 + ((key >> 3) ^ fm)) * 8 + (key & 7)] = f32_to_bf16(e);
        }
#pragma unroll
        for (int msk = 1; msk < 16; msk <<= 1) rs += __shfl_xor(rs, msk, 64);
        float alpha = __expf(m_run[r] - m_new);
        l_run[r] = l_run[r] * alpha + rs;
        m_run[r] = m_new;
#pragma unroll
        for (int nt = 0; nt < 8; ++nt) accO[nt][r] *= alpha;
    }
}

__global__ __launch_bounds__(256) void flash_attn(const bhalf* __restrict__ Qb,
                                                  const bhalf* __restrict__ Kb,
                                                  const bhalf* __restrict__ VT,
                                                  const float* __restrict__ amask,
                                                  float* __restrict__ out) {
    __shared__ __align__(16) bhalf Ks[64 * 128];    // 1024 slots, swizzled
    __shared__ __align__(16) bhalf VTs[128 * 64];   // 1024 slots, swizzled
    __shared__ __align__(16) bhalf Ps[8 * 16 * 64]; // 8 regions x 1024, swizzled
    const int tid = threadIdx.x, lane = tid & 63, w = tid >> 6;
    const int quad = lane >> 4, l = lane & 15;
    const int qt = blockIdx.x, bh = blockIdx.y;
    const int b = bh >> 4, h = bh & 15;
    const int row_lo = qt * 64 + w * 16;
    const int row_hi = (31 - qt) * 64 + w * 16;
    const int ch_hi = 32 - qt;                      // 64-key chunks for hi tile

    // Q A-fragments for both tiles: A[m=l][k=ks*32+quad*8+j]
    s16x8 qfl[4], qfh[4];
    {
        const bhalf* Qlo = Qb + (size_t)(b * S_ + row_lo + l) * HID_ + h * HD_;
        const bhalf* Qhi = Qb + (size_t)(b * S_ + row_hi + l) * HID_ + h * HD_;
#pragma unroll
        for (int ks = 0; ks < 4; ++ks) {
            qfl[ks] = *(const s16x8*)(Qlo + ks * 32 + quad * 8);
            qfh[ks] = *(const s16x8*)(Qhi + ks * 32 + quad * 8);
        }
    }
    float mh[4], lh[4], ml[4], ll[4];
#pragma unroll
    for (int r = 0; r < 4; ++r) { mh[r] = -1e30f; ml[r] = -1e30f; lh[r] = 0.f; ll[r] = 0.f; }
    f32x4 aoh[8] = {}, aol[8] = {};
    bhalf* Pw_hi = Ps + (w * 2 + 0) * 1024;
    bhalf* Pw_lo = Ps + (w * 2 + 1) * 1024;

    for (int kc = 0; kc < ch_hi; ++kc) {
        // ---- stage K (64x128) and V^T (128x64) chunks, swizzled ----
#pragma unroll
        for (int j = 0; j < 4; ++j) {
            int slot0 = (w * 4 + j) * 64;           // wave-uniform
            int slot  = slot0 + lane;
            {
                int key = slot >> 4, dgs = slot & 15;
                int dg  = (dgs & 8) | ((dgs ^ key) & 7);
                gl_lds16(Kb + (size_t)(b * S_ + kc * 64 + key) * HID_ + h * HD_ + dg * 8,
                         Ks + slot0 * 8);
            }
            {
                int d = slot >> 3, kg = ((slot & 7) ^ d) & 7;
                gl_lds16(VT + ((size_t)bh * HD_ + d) * S_ + kc * 64 + kg * 8,
                         VTs + slot0 * 8);
            }
        }
        __syncthreads();

        const bool lo_act = (kc <= qt);
        const bool dg_hi  = (kc == ch_hi - 1);
        const bool dg_lo  = (kc == qt);
        const int  key0   = kc * 64;
        float am[4];
#pragma unroll
        for (int nt = 0; nt < 4; ++nt) am[nt] = amask[b * S_ + key0 + nt * 16 + l];

        // ---- QK^T: shared K fragments ----
        f32x4 sh[4] = {}, sl[4] = {};
        if (lo_act) {
#pragma unroll
            for (int nt = 0; nt < 4; ++nt) {
                int key = nt * 16 + l;
#pragma unroll
                for (int ks = 0; ks < 4; ++ks) {
                    int dg  = ks * 4 + quad;
                    int dgs = (dg & 8) | ((dg ^ key) & 7);
                    s16x8 kf = *(const s16x8*)(Ks + (key * 16 + dgs) * 8);
                    sh[nt] = __builtin_amdgcn_mfma_f32_16x16x32_bf16(qfh[ks], kf, sh[nt], 0, 0, 0);
                    sl[nt] = __builtin_amdgcn_mfma_f32_16x16x32_bf16(qfl[ks], kf, sl[nt], 0, 0, 0);
                }
            }
        } else {
#pragma unroll
            for (int nt = 0; nt < 4; ++nt) {
                int key = nt * 16 + l;
#pragma unroll
                for (int ks = 0; ks < 4; ++ks) {
                    int dg  = ks * 4 + quad;
                    int dgs = (dg & 8) | ((dg ^ key) & 7);
                    s16x8 kf = *(const s16x8*)(Ks + (key * 16 + dgs) * 8);
                    sh[nt] = __builtin_amdgcn_mfma_f32_16x16x32_bf16(qfh[ks], kf, sh[nt], 0, 0, 0);
                }
            }
        }
        softmax_tile(sh, mh, lh, aoh, Pw_hi, row_hi, dg_hi, key0, am, quad, l);
        if (lo_act) softmax_tile(sl, ml, ll, aol, Pw_lo, row_lo, dg_lo, key0, am, quad, l);

        // ---- PV: shared V fragments ----
        const int fl = (l + (l >> 3)) & 7;
        if (lo_act) {
#pragma unroll
            for (int kstep = 0; kstep < 2; ++kstep) {
                int kg = kstep * 4 + quad;
                s16x8 pfh = *(const s16x8*)(Pw_hi + (l * 8 + (kg ^ fl)) * 8);
                s16x8 pfl = *(const s16x8*)(Pw_lo + (l * 8 + (kg ^ fl)) * 8);
#pragma unroll
                for (int nt = 0; nt < 8; ++nt) {
                    int d = nt * 16 + l;
                    s16x8 vf = *(const s16x8*)(VTs + (d * 8 + (kg ^ (d & 7))) * 8);
                    aoh[nt] = __builtin_amdgcn_mfma_f32_16x16x32_bf16(pfh, vf, aoh[nt], 0, 0, 0);
                    aol[nt] = __builtin_amdgcn_mfma_f32_16x16x32_bf16(pfl, vf, aol[nt], 0, 0, 0);
                }
            }
        } else {
#pragma unroll
            for (int kstep = 0; kstep < 2; ++kstep) {
                int kg = kstep * 4 + quad;
                s16x8 pfh = *(const s16x8*)(Pw_hi + (l * 8 + (kg ^ fl)) * 8);
#pragma unroll
                for (int nt = 0; nt < 8; ++nt) {
                    int d = nt * 16 + l;
                    s16x8 vf = *(const s16x8*)(VTs + (d * 8 + (kg ^ (d & 7))) * 8);
                    aoh[nt] = __builtin_amdgcn_mfma_f32_16x16x32_bf16(pfh, vf, aoh[nt], 0, 0, 0);
                }
            }
        }
        __syncthreads();
    }

    // ---- epilogue: O /= l, fp32 out (B,S,HID) ----
    float invh[4], invl[4];
#pragma unroll
    for (int r = 0; r < 4; ++r) { invh[r] = 1.f / lh[r]; invl[r] = 1.f / ll[r]; }
#pragma unroll
    for (int nt = 0; nt < 8; ++nt) {
        int col = h * HD_ + nt * 16 + l;
#pragma unroll
        for (int r = 0; r < 4; ++r) {
            out[(size_t)(b * S_ + row_hi + quad * 4 + r) * HID_ + col] = aoh[nt][r] * invh[r];
            out[(size_t)(b * S_ + row_lo + quad * 4 + r) * HID_ + col] = aol[nt][r] * invl[r];
        }
    }
}

extern "C" void kernel_launch(void* const* d_in, const int* in_sizes, int n_in,
                              void* d_out, int out_size, void* d_ws, size_t ws_size,
                              hipStream_t stream) {
    const float* hs    = (const float*)d_in[0];
    const float* amask = (const float*)d_in[1];
    const float* Wq    = (const float*)d_in[2];
    const float* bq    = (const float*)d_in[3];
    const float* Wk    = (const float*)d_in[4];
    const float* bk    = (const float*)d_in[5];
    const float* Wv    = (const float*)d_in[6];
    const float* bv    = (const float*)d_in[7];
    float* out = (float*)d_out;

    bhalf* hsb = (bhalf*)d_ws;              // 8,388,608 elems
    bhalf* wqb = hsb + 8388608;             // 3 x 4,194,304 (contiguous)
    bhalf* wkb = wqb + 4194304;
    bhalf* wvb = wkb + 4194304;
    bhalf* Qb  = wvb + 4194304;             // 3 x 8,388,608 (contiguous)
    bhalf* Kb  = Qb + 8388608;
    bhalf* Vb  = Kb + 8388608;
    bhalf* VTb = Vb + 8388608;              // total ~109 MB

    cast_f32_bf16<<<8192, 256, 0, stream>>>(hs, hsb, 2097152);
    cast_f32_bf16<<<4096, 256, 0, stream>>>(Wq, wqb, 1048576);
    cast_f32_bf16<<<4096, 256, 0, stream>>>(Wk, wkb, 1048576);
    cast_f32_bf16<<<4096, 256, 0, stream>>>(Wv, wvb, 1048576);
    qkv_gemm<<<dim3(32, 16, 3), 256, 0, stream>>>(hsb, wqb, bq, bk, bv, Qb);
    rope_kernel<<<8192, 256, 0, stream>>>(Qb, Kb);
    v_transpose<<<dim3(64, 4, 32), 256, 0, stream>>>(Vb, VTb);
    flash_attn<<<dim3(16, 32), 256, 0, stream>>>(Qb, Kb, VTb, amask, out);
}

// Round 3
// 398.928 us; speedup vs baseline: 1.5175x; 1.0746x over previous
//
#include <hip/hip_runtime.h>

typedef unsigned short bhalf;          // bf16 bits
typedef __attribute__((ext_vector_type(4))) float    f32x4;
typedef __attribute__((ext_vector_type(8))) short    s16x8;
typedef __attribute__((ext_vector_type(4))) float    floatx4;
typedef __attribute__((ext_vector_type(4))) unsigned int u32x4;
typedef __attribute__((ext_vector_type(4))) unsigned short u16x4;

#define B_  2
#define S_  2048
#define HID_ 2048
#define NH_ 16
#define HD_ 128
#define M_  (B_*S_)          // 4096
#define MASKV (-10000.0f)

__device__ __forceinline__ bhalf f32_to_bf16(float f) {
    union { float f; unsigned int u; } v; v.f = f;
    unsigned int r = v.u + 0x7FFFu + ((v.u >> 16) & 1u);   // RNE
    return (bhalf)(r >> 16);
}
__device__ __forceinline__ bhalf f32_to_bf16_trunc(float f) {
    union { float f; unsigned int u; } v; v.f = f;
    return (bhalf)(v.u >> 16);
}
__device__ __forceinline__ float bf16_to_f32(bhalf h) {
    union { unsigned int u; float f; } v; v.u = ((unsigned int)h) << 16;
    return v.f;
}

// async global->LDS, 16B per lane; LDS dest = wave-uniform base + lane*16
__device__ __forceinline__ void gl_lds16(const void* g, void* l) {
    __builtin_amdgcn_global_load_lds(
        (const __attribute__((address_space(1))) void*)g,
        (__attribute__((address_space(3))) void*)l, 16, 0, 0);
}

// ---------------- fused cast fp32 -> bf16 for hs + Wq + Wk + Wv ------------
// dst layout (contiguous): hsb | wq | wk | wv  (float4 slots)
__global__ __launch_bounds__(256) void cast_all(const float* __restrict__ hs,
                                                const float* __restrict__ Wq,
                                                const float* __restrict__ Wk,
                                                const float* __restrict__ Wv,
                                                bhalf* __restrict__ dst) {
    int idx = blockIdx.x * 256 + threadIdx.x;           // 0 .. 5,242,879
    const float* src;
    if (idx < 2097152)      src = hs + (size_t)idx * 4;
    else if (idx < 3145728) src = Wq + (size_t)(idx - 2097152) * 4;
    else if (idx < 4194304) src = Wk + (size_t)(idx - 3145728) * 4;
    else                    src = Wv + (size_t)(idx - 4194304) * 4;
    floatx4 f = *(const floatx4*)src;
    u16x4 o;
    o.x = f32_to_bf16(f.x); o.y = f32_to_bf16(f.y);
    o.z = f32_to_bf16(f.z); o.w = f32_to_bf16(f.w);
    *(u16x4*)(dst + (size_t)idx * 4) = o;
}

// ---------------- fused QKV GEMM (m97 rung): out = hs @ W^T + b ------------
__global__ __launch_bounds__(256) void qkv_gemm(const bhalf* __restrict__ A,
                                                const bhalf* __restrict__ Wb,
                                                const float* __restrict__ bq,
                                                const float* __restrict__ bk,
                                                const float* __restrict__ bv,
                                                bhalf* __restrict__ Out) {
    __shared__ __align__(16) bhalf As[128 * 32];
    __shared__ __align__(16) bhalf Bs[128 * 32];
    const int tid  = threadIdx.x;
    const int lane = tid & 63, w = tid >> 6;
    const int wy = w >> 1, wx = w & 1;
    const int quad = lane >> 4, l = lane & 15;
    const int m0 = blockIdx.x * 128, n0 = blockIdx.y * 128;
    const int z  = blockIdx.z;
    const bhalf* W    = Wb + (size_t)z * HID_ * HID_;
    const float* bias = (z == 0) ? bq : (z == 1) ? bk : bv;
    bhalf* out        = Out + (size_t)z * M_ * HID_;

    f32x4 acc[4][4] = {};

    for (int kt = 0; kt < HID_; kt += 32) {
#pragma unroll
        for (int j = 0; j < 2; ++j) {
            int slot0 = j * 256 + w * 64;          // wave-uniform
            int slot  = slot0 + lane;
            int row = slot >> 2;
            int cg  = (slot & 3) ^ ((row >> 1) & 3);   // swizzle
            gl_lds16(A + (size_t)(m0 + row) * HID_ + kt + cg * 8, As + slot0 * 8);
            gl_lds16(W + (size_t)(n0 + row) * HID_ + kt + cg * 8, Bs + slot0 * 8);
        }
        __syncthreads();
        s16x8 af[4], bfr[4];
#pragma unroll
        for (int mt = 0; mt < 4; ++mt) {
            int row = wy * 64 + mt * 16 + l;
            int cgs = quad ^ ((row >> 1) & 3);
            af[mt] = *(const s16x8*)(As + (row * 4 + cgs) * 8);
        }
#pragma unroll
        for (int nt = 0; nt < 4; ++nt) {
            int row = wx * 64 + nt * 16 + l;
            int cgs = quad ^ ((row >> 1) & 3);
            bfr[nt] = *(const s16x8*)(Bs + (row * 4 + cgs) * 8);
        }
#pragma unroll
        for (int mt = 0; mt < 4; ++mt)
#pragma unroll
            for (int nt = 0; nt < 4; ++nt)
                acc[mt][nt] = __builtin_amdgcn_mfma_f32_16x16x32_bf16(
                    af[mt], bfr[nt], acc[mt][nt], 0, 0, 0);
        __syncthreads();
    }
#pragma unroll
    for (int mt = 0; mt < 4; ++mt) {
#pragma unroll
        for (int nt = 0; nt < 4; ++nt) {
            int col = n0 + wx * 64 + nt * 16 + l;
            float bv_ = bias[col];
#pragma unroll
            for (int r = 0; r < 4; ++r) {
                int row = m0 + wy * 64 + mt * 16 + quad * 4 + r;
                out[(size_t)row * HID_ + col] = f32_to_bf16(acc[mt][nt][r] + bv_);
            }
        }
    }
}

// ---------------- RoPE: table precompute + apply ---------------------------
__global__ __launch_bounds__(256) void rope_table(float2* __restrict__ tab) {
    int idx = blockIdx.x * 256 + threadIdx.x;   // 65536 = 2048 s x 32 i
    int i = idx & 31, s = idx >> 5;
    float inv = expf(-(float)i * 0.2878231366242557f);   // ln(10000)/32
    float ang = (float)s * inv;
    tab[idx] = make_float2(sinf(ang), cosf(ang));
}

__global__ __launch_bounds__(256) void rope_apply(bhalf* __restrict__ Qb,
                                                  bhalf* __restrict__ Kb,
                                                  const float2* __restrict__ tab) {
    int flat = blockIdx.x * 256 + threadIdx.x;   // 2,097,152
    int i = flat & 31;
    int h = (flat >> 5) & 15;
    int s = (flat >> 9) & 2047;
    int b = flat >> 20;
    size_t base = ((size_t)(b * S_ + s)) * HID_ + h * HD_ + 2 * i;
    float2 sc = tab[s * 32 + i];
    float c = sc.y, sn = sc.x;
    {
        unsigned int q = *(const unsigned int*)(Qb + base);
        float x0 = bf16_to_f32((bhalf)(q & 0xffff));
        float x1 = bf16_to_f32((bhalf)(q >> 16));
        unsigned int o = (unsigned int)f32_to_bf16(x0 * c - x1 * sn)
                       | ((unsigned int)f32_to_bf16(x1 * c + x0 * sn) << 16);
        *(unsigned int*)(Qb + base) = o;
    }
    {
        unsigned int k = *(const unsigned int*)(Kb + base);
        float x0 = bf16_to_f32((bhalf)(k & 0xffff));
        float x1 = bf16_to_f32((bhalf)(k >> 16));
        unsigned int o = (unsigned int)f32_to_bf16(x0 * c - x1 * sn)
                       | ((unsigned int)f32_to_bf16(x1 * c + x0 * sn) << 16);
        *(unsigned int*)(Kb + base) = o;
    }
}

// ---------------- V transpose per (b,h): (S x HD) -> (HD x S) --------------
__global__ __launch_bounds__(256) void v_transpose(const bhalf* __restrict__ Vb,
                                                   bhalf* __restrict__ VT) {
    __shared__ bhalf tile[32 * 33];
    int t = threadIdx.x;
    int s0 = blockIdx.x * 32, d0 = blockIdx.y * 32, bh = blockIdx.z;
    int b = bh >> 4, h = bh & 15;
    {
        int sl = t >> 3, dg = t & 7;
        u16x4 v = *(const u16x4*)(Vb + (size_t)(b * S_ + s0 + sl) * HID_ + h * HD_ + d0 + dg * 4);
        tile[sl * 33 + dg * 4 + 0] = v.x;
        tile[sl * 33 + dg * 4 + 1] = v.y;
        tile[sl * 33 + dg * 4 + 2] = v.z;
        tile[sl * 33 + dg * 4 + 3] = v.w;
    }
    __syncthreads();
    {
        int dl = t >> 3, sg = t & 7;
        u16x4 v;
        v.x = tile[(sg * 4 + 0) * 33 + dl];
        v.y = tile[(sg * 4 + 1) * 33 + dl];
        v.z = tile[(sg * 4 + 2) * 33 + dl];
        v.w = tile[(sg * 4 + 3) * 33 + dl];
        *(u16x4*)(VT + ((size_t)(b * NH_ + h) * HD_ + d0 + dl) * S_ + s0 + sg * 4) = v;
    }
}

// ---------------- flash attention, paired 64-row q-tiles, 128-key chunks ---
// Ks  [key=128][x=16]  x = dg ^ (key&7) on low3          (32 KB)
// VTs [d=128][x=16]    x = kg ^ (d&7) on low3            (32 KB)
// Ps  per wave [m=16][x=16] x = kg ^ fp(m), fp=(m>>1&6)|(m&1)  (16 KB)
__device__ __forceinline__ void softmax8(const f32x4* sc, float* m_run, f32x4& l_acc,
        f32x4* accO, bhalf* Pw, int row_base, bool diag, int key0,
        const float* am, int quad, int l) {
#pragma unroll
    for (int r = 0; r < 4; ++r) {
        const int qrow = row_base + quad * 4 + r;
        float p[8];
#pragma unroll
        for (int nt = 0; nt < 8; ++nt) {
            float v = sc[nt][r] * 0.08838834764831845f;   // 1/sqrt(128)
            if (diag) { int key = key0 + nt * 16 + l; v = (key > qrow) ? MASKV : v; }
            p[nt] = v + am[nt];
        }
        float mx = fmaxf(fmaxf(fmaxf(p[0], p[1]), fmaxf(p[2], p[3])),
                         fmaxf(fmaxf(p[4], p[5]), fmaxf(p[6], p[7])));
#pragma unroll
        for (int msk = 1; msk < 16; msk <<= 1) mx = fmaxf(mx, __shfl_xor(mx, msk, 64));
        float m_new = fmaxf(m_run[r], mx);
        float alpha = __expf(m_run[r] - m_new);
        m_run[r] = m_new;
        const int m  = quad * 4 + r;
        const int fm = (quad << 1) | (r & 1);
#pragma unroll
        for (int nt = 0; nt < 8; ++nt) {
            float e = __expf(p[nt] - m_new);
            int key = nt * 16 + l;
            Pw[(m * 16 + ((key >> 3) ^ fm)) * 8 + (key & 7)] = f32_to_bf16_trunc(e);
        }
        l_acc[r] *= alpha;
#pragma unroll
        for (int nt = 0; nt < 8; ++nt) accO[nt][r] *= alpha;
    }
}

__global__ __launch_bounds__(256) void flash_attn(const bhalf* __restrict__ Qb,
                                                  const bhalf* __restrict__ Kb,
                                                  const bhalf* __restrict__ VT,
                                                  const float* __restrict__ amask,
                                                  float* __restrict__ out) {
    __shared__ __align__(16) bhalf Ks[128 * 128];   // 2048 slots x 16B
    __shared__ __align__(16) bhalf VTs[128 * 128];  // 2048 slots x 16B
    __shared__ __align__(16) bhalf Ps[4 * 16 * 128];// 4 wave regions x 2048 elems
    const int tid = threadIdx.x, lane = tid & 63, w = tid >> 6;
    const int quad = lane >> 4, l = lane & 15;
    const int qt = blockIdx.x, bh = blockIdx.y;
    const int b = bh >> 4, h = bh & 15;
    const int row_lo = qt * 64 + w * 16;
    const int row_hi = (31 - qt) * 64 + w * 16;
    const int ch_hi   = (33 - qt) >> 1;             // # 128-key chunks (hi tile)
    const int lo_last = (qt * 64 + 63) >> 7;        // last active chunk (lo tile)

    // Q A-fragments: A[m=l][k=ks*32+quad*8+j]
    s16x8 qfl[4], qfh[4];
    {
        const bhalf* Qlo = Qb + (size_t)(b * S_ + row_lo + l) * HID_ + h * HD_;
        const bhalf* Qhi = Qb + (size_t)(b * S_ + row_hi + l) * HID_ + h * HD_;
#pragma unroll
        for (int ks = 0; ks < 4; ++ks) {
            qfl[ks] = *(const s16x8*)(Qlo + ks * 32 + quad * 8);
            qfh[ks] = *(const s16x8*)(Qhi + ks * 32 + quad * 8);
        }
    }
    // ones B-fragment (bf16 1.0) for the row-sum MFMA
    s16x8 ones;
#pragma unroll
    for (int j = 0; j < 8; ++j) ones[j] = (short)0x3F80;

    float mh[4], ml[4];
#pragma unroll
    for (int r = 0; r < 4; ++r) { mh[r] = -1e30f; ml[r] = -1e30f; }
    f32x4 lh = {}, ll = {};
    f32x4 aoh[8] = {}, aol[8] = {};
    bhalf* Pw = Ps + w * 2048;
    const int fpl = ((l >> 2) << 1) | (l & 1);      // fp(m=l) for Ps reads

    for (int kc = 0; kc < ch_hi; ++kc) {
        const int key0 = kc * 128;
        // ---- stage K (128x128) and V^T (128x128) swizzled, 16 loads/thread ----
#pragma unroll
        for (int j = 0; j < 8; ++j) {
            int slot0 = j * 256 + w * 64;           // wave-uniform
            int slot  = slot0 + lane;
            int row = slot >> 4, x = slot & 15;
            int g   = (x & 8) | ((x ^ row) & 7);
            gl_lds16(Kb + (size_t)(b * S_ + key0 + row) * HID_ + h * HD_ + g * 8,
                     Ks + slot0 * 8);
            gl_lds16(VT + ((size_t)bh * HD_ + row) * S_ + key0 + g * 8,
                     VTs + slot0 * 8);
        }
        __syncthreads();

        const bool lo_act = (kc <= lo_last);
        const bool dg_hi  = (kc == ch_hi - 1);
        const bool dg_lo  = (kc == lo_last);
        float am[8];
#pragma unroll
        for (int nt = 0; nt < 8; ++nt) am[nt] = amask[b * S_ + key0 + nt * 16 + l];

        // ---- QK^T: K fragments shared across both tiles ----
        f32x4 sh[8] = {}, sl[8] = {};
        if (lo_act) {
#pragma unroll
            for (int nt = 0; nt < 8; ++nt) {
                int key = nt * 16 + l;
#pragma unroll
                for (int ks = 0; ks < 4; ++ks) {
                    int dg = ks * 4 + quad;
                    int x  = (dg & 8) | ((dg ^ key) & 7);
                    s16x8 kf = *(const s16x8*)(Ks + (key * 16 + x) * 8);
                    sh[nt] = __builtin_amdgcn_mfma_f32_16x16x32_bf16(qfh[ks], kf, sh[nt], 0, 0, 0);
                    sl[nt] = __builtin_amdgcn_mfma_f32_16x16x32_bf16(qfl[ks], kf, sl[nt], 0, 0, 0);
                }
            }
        } else {
#pragma unroll
            for (int nt = 0; nt < 8; ++nt) {
                int key = nt * 16 + l;
#pragma unroll
                for (int ks = 0; ks < 4; ++ks) {
                    int dg = ks * 4 + quad;
                    int x  = (dg & 8) | ((dg ^ key) & 7);
                    s16x8 kf = *(const s16x8*)(Ks + (key * 16 + x) * 8);
                    sh[nt] = __builtin_amdgcn_mfma_f32_16x16x32_bf16(qfh[ks], kf, sh[nt], 0, 0, 0);
                }
            }
        }

        // ---- hi tile: softmax -> P -> PV (+ ones row-sum) ----
        softmax8(sh, mh, lh, aoh, Pw, row_hi, dg_hi, key0, am, quad, l);
#pragma unroll
        for (int kstep = 0; kstep < 4; ++kstep) {
            int kg = kstep * 4 + quad;
            s16x8 pf = *(const s16x8*)(Pw + (l * 16 + (kg ^ fpl)) * 8);
            lh = __builtin_amdgcn_mfma_f32_16x16x32_bf16(pf, ones, lh, 0, 0, 0);
#pragma unroll
            for (int nt = 0; nt < 8; ++nt) {
                int d = nt * 16 + l;
                int x = (kg & 8) | ((kg ^ d) & 7);
                s16x8 vf = *(const s16x8*)(VTs + (d * 16 + x) * 8);
                aoh[nt] = __builtin_amdgcn_mfma_f32_16x16x32_bf16(pf, vf, aoh[nt], 0, 0, 0);
            }
        }
        // ---- lo tile ----
        if (lo_act) {
            softmax8(sl, ml, ll, aol, Pw, row_lo, dg_lo, key0, am, quad, l);
#pragma unroll
            for (int kstep = 0; kstep < 4; ++kstep) {
                int kg = kstep * 4 + quad;
                s16x8 pf = *(const s16x8*)(Pw + (l * 16 + (kg ^ fpl)) * 8);
                ll = __builtin_amdgcn_mfma_f32_16x16x32_bf16(pf, ones, ll, 0, 0, 0);
#pragma unroll
                for (int nt = 0; nt < 8; ++nt) {
                    int d = nt * 16 + l;
                    int x = (kg & 8) | ((kg ^ d) & 7);
                    s16x8 vf = *(const s16x8*)(VTs + (d * 16 + x) * 8);
                    aol[nt] = __builtin_amdgcn_mfma_f32_16x16x32_bf16(pf, vf, aol[nt], 0, 0, 0);
                }
            }
        }
        __syncthreads();   // all waves done reading before next staging
    }

    // ---- epilogue: O /= l, fp32 out (B,S,HID) ----
    float invh[4], invl[4];
#pragma unroll
    for (int r = 0; r < 4; ++r) { invh[r] = 1.f / lh[r]; invl[r] = 1.f / ll[r]; }
#pragma unroll
    for (int nt = 0; nt < 8; ++nt) {
        int col = h * HD_ + nt * 16 + l;
#pragma unroll
        for (int r = 0; r < 4; ++r) {
            out[(size_t)(b * S_ + row_hi + quad * 4 + r) * HID_ + col] = aoh[nt][r] * invh[r];
            out[(size_t)(b * S_ + row_lo + quad * 4 + r) * HID_ + col] = aol[nt][r] * invl[r];
        }
    }
}

extern "C" void kernel_launch(void* const* d_in, const int* in_sizes, int n_in,
                              void* d_out, int out_size, void* d_ws, size_t ws_size,
                              hipStream_t stream) {
    const float* hs    = (const float*)d_in[0];
    const float* amask = (const float*)d_in[1];
    const float* Wq    = (const float*)d_in[2];
    const float* bq    = (const float*)d_in[3];
    const float* Wk    = (const float*)d_in[4];
    const float* bk    = (const float*)d_in[5];
    const float* Wv    = (const float*)d_in[6];
    const float* bv    = (const float*)d_in[7];
    float* out = (float*)d_out;

    bhalf* hsb = (bhalf*)d_ws;              // 8,388,608 elems
    bhalf* wqb = hsb + 8388608;             // 3 x 4,194,304 (contiguous)
    bhalf* wkb = wqb + 4194304;
    bhalf* wvb = wkb + 4194304;
    bhalf* Qb  = wvb + 4194304;             // 3 x 8,388,608 (contiguous)
    bhalf* Kb  = Qb + 8388608;
    bhalf* Vb  = Kb + 8388608;
    bhalf* VTb = Vb + 8388608;
    float2* tab = (float2*)(VTb + 8388608); // 65536 float2 = 512 KB

    rope_table<<<256, 256, 0, stream>>>(tab);
    cast_all<<<20480, 256, 0, stream>>>(hs, Wq, Wk, Wv, hsb);
    qkv_gemm<<<dim3(32, 16, 3), 256, 0, stream>>>(hsb, wqb, bq, bk, bv, Qb);
    rope_apply<<<8192, 256, 0, stream>>>(Qb, Kb, tab);
    v_transpose<<<dim3(64, 4, 32), 256, 0, stream>>>(Vb, VTb);
    flash_attn<<<dim3(16, 32), 256, 0, stream>>>(Qb, Kb, VTb, amask, out);
}